// Round 4
// baseline (69.574 us; speedup 1.0000x reference)
//
#include <hip/hip_runtime.h>

// CCAMDec: out = x + scale * softmax(max_k(E)-E) @ y,  E = x·yᵀ over HW
// N=8, C=512, K=64, HW=4096. softmax(max-E) == softmax(-E) (shift invariance).
#define N_ 8
#define C_ 512
#define K_ 64
#define HW_ 4096
#define SPLITS 16
#define SRANGE (HW_ / SPLITS)   // 256

typedef __attribute__((ext_vector_type(8))) short short8;   // 8 bf16 (4 VGPRs) MFMA A/B frag
typedef __attribute__((ext_vector_type(4))) float floatx4;  // MFMA C/D frag

__device__ __forceinline__ float bf2f(unsigned short b){
  union { unsigned u; float f; } v; v.u = ((unsigned)b) << 16;
  return v.f;
}

// 8 f32 -> 8 bf16 via hardware v_cvt_pk_bf16_f32 (RNE, 1 instr / 2 elems)
__device__ __forceinline__ short8 cvt8(const float* __restrict__ p){
  float4 u = *(const float4*)p;
  float4 w = *(const float4*)(p + 4);
  union { unsigned u32[4]; short8 s; } r;
  asm("v_cvt_pk_bf16_f32 %0, %1, %2" : "=v"(r.u32[0]) : "v"(u.x), "v"(u.y));
  asm("v_cvt_pk_bf16_f32 %0, %1, %2" : "=v"(r.u32[1]) : "v"(u.z), "v"(u.w));
  asm("v_cvt_pk_bf16_f32 %0, %1, %2" : "=v"(r.u32[2]) : "v"(w.x), "v"(w.y));
  asm("v_cvt_pk_bf16_f32 %0, %1, %2" : "=v"(r.u32[3]) : "v"(w.z), "v"(w.w));
  return r.s;
}

// K0: y (f32, [n][k][s]) -> ybf (bf16 row-major [n][k][s]) and ytr (bf16 [n][s][k])
__global__ __launch_bounds__(256) void k_prep(const float* __restrict__ y,
                                              unsigned short* __restrict__ ybf,
                                              unsigned short* __restrict__ ytr){
  __shared__ unsigned short tile[64][72];
  int n  = blockIdx.x >> 6;                 // 64 s-tiles per batch
  int s0 = (blockIdx.x & 63) << 6;
  int tid = threadIdx.x;
  int k  = tid >> 2;
  int sc = (tid & 3) << 4;
  const float* yp = y + ((size_t)n * K_ + k) * HW_ + s0 + sc;
  union { unsigned short u16[16]; short8 s8[2]; uint4 q[2]; } u;
  u.s8[0] = cvt8(yp);
  u.s8[1] = cvt8(yp + 8);
  unsigned short* rp = ybf + ((size_t)n * K_ + k) * HW_ + s0 + sc;
  *(uint4*)rp       = u.q[0];
  *(uint4*)(rp + 8) = u.q[1];
#pragma unroll
  for (int j = 0; j < 16; ++j) tile[sc + j][k] = u.u16[j];
  __syncthreads();
  int s  = tid >> 2;
  int kc = (tid & 3) << 4;
  unsigned short* tp = ytr + ((size_t)n * HW_ + s0 + s) * K_ + kc;
  *(uint4*)tp       = *(const uint4*)&tile[s][kc];
  *(uint4*)(tp + 8) = *(const uint4*)&tile[s][kc + 8];
}

// K1: partial energies. 4 waves/block, each wave owns one sp (s-range of 256)
// and computes a 16c x 64k tile. Also stores x as bf16 (xbf) exactly once.
template<bool WRITE_XBF>
__global__ __launch_bounds__(256, 4) void k_energy(const float* __restrict__ x,
                                                   const unsigned short* __restrict__ ybf,
                                                   float* __restrict__ partial,
                                                   unsigned short* __restrict__ xbf){
  int bid = blockIdx.x;           // 8n * 32ct * 4spg = 1024
  int spg = bid & 3;
  int ct  = (bid >> 2) & 31;
  int n   = bid >> 7;
  int w   = threadIdx.x >> 6;
  int sp  = spg * 4 + w;          // 0..15
  int l   = threadIdx.x & 63;
  int lo = l & 15, hi = l >> 4;
  int c0 = ct << 4;
  int sb = sp * SRANGE;

  const float*          xp  = x   + ((size_t)n * C_ + c0 + lo) * HW_ + hi * 8;
  const unsigned short* yp  = ybf + ((size_t)n * K_ + lo) * HW_ + hi * 8;
  unsigned short*       xbp = xbf + ((size_t)n * C_ + c0 + lo) * HW_ + hi * 8;

  floatx4 acc0 = {0.f,0.f,0.f,0.f};
  floatx4 acc1 = acc0, acc2 = acc0, acc3 = acc0;

  for (int s = sb; s < sb + SRANGE; s += 64){
    short8 a0 = cvt8(xp + s);
    short8 a1 = cvt8(xp + s + 32);
    if (WRITE_XBF){
      *(short8*)(xbp + s)      = a0;   // dense: 16 rows x 64B segments per instr
      *(short8*)(xbp + s + 32) = a1;
    }
    short8 b00 = *(const short8*)(yp + s);
    short8 b10 = *(const short8*)(yp + s + 16 * HW_);
    short8 b20 = *(const short8*)(yp + s + 32 * HW_);
    short8 b30 = *(const short8*)(yp + s + 48 * HW_);
    short8 b01 = *(const short8*)(yp + s + 32);
    short8 b11 = *(const short8*)(yp + s + 32 + 16 * HW_);
    short8 b21 = *(const short8*)(yp + s + 32 + 32 * HW_);
    short8 b31 = *(const short8*)(yp + s + 32 + 48 * HW_);
    acc0 = __builtin_amdgcn_mfma_f32_16x16x32_bf16(a0, b00, acc0, 0, 0, 0);
    acc1 = __builtin_amdgcn_mfma_f32_16x16x32_bf16(a0, b10, acc1, 0, 0, 0);
    acc2 = __builtin_amdgcn_mfma_f32_16x16x32_bf16(a0, b20, acc2, 0, 0, 0);
    acc3 = __builtin_amdgcn_mfma_f32_16x16x32_bf16(a0, b30, acc3, 0, 0, 0);
    acc0 = __builtin_amdgcn_mfma_f32_16x16x32_bf16(a1, b01, acc0, 0, 0, 0);
    acc1 = __builtin_amdgcn_mfma_f32_16x16x32_bf16(a1, b11, acc1, 0, 0, 0);
    acc2 = __builtin_amdgcn_mfma_f32_16x16x32_bf16(a1, b21, acc2, 0, 0, 0);
    acc3 = __builtin_amdgcn_mfma_f32_16x16x32_bf16(a1, b31, acc3, 0, 0, 0);
  }

  // D layout: col = l&15 (k within tile), row = (l>>4)*4 + reg  [m89-verified]
  float* pp = partial + (((size_t)sp * N_ + n) * C_ + c0) * K_;
#pragma unroll
  for (int r = 0; r < 4; ++r){
    size_t coff = (size_t)(hi * 4 + r) * K_;
    pp[coff +  0 + lo] = acc0[r];
    pp[coff + 16 + lo] = acc1[r];
    pp[coff + 32 + lo] = acc2[r];
    pp[coff + 48 + lo] = acc3[r];
  }
}

// K2: reduce splits + softmax(-E) over k (wave-wide, K=64=wavefront), att -> bf16
__global__ __launch_bounds__(256) void k_softmax(const float* __restrict__ partial,
                                                 unsigned short* __restrict__ att){
  int wid = blockIdx.x * 4 + (threadIdx.x >> 6);  // (n,c) row id, 0..4095
  int l = threadIdx.x & 63;
  size_t base = (size_t)wid * K_ + l;
  float e = 0.f;
#pragma unroll
  for (int sp = 0; sp < SPLITS; ++sp) e += partial[(size_t)sp * (N_*C_*K_) + base];
  // softmax(-e): stabilize with min(e)
  float m = e;
#pragma unroll
  for (int off = 32; off > 0; off >>= 1) m = fminf(m, __shfl_xor(m, off));
  float p = __expf(m - e);
  float sum = p;
#pragma unroll
  for (int off = 32; off > 0; off >>= 1) sum += __shfl_xor(sum, off);
  union { unsigned u; float f; } v; v.f = p / sum;
  unsigned r = v.u + 0x7FFFu + ((v.u >> 16) & 1u);
  att[base] = (unsigned short)(r >> 16);
}

// K3: out = x + scale * att @ y.  4 waves/block; block tile 16c x 512s
// (128s per wave). Epilogue: per 32-s double-subtile, transpose acc through
// LDS so each lane owns (1 row, 8 consecutive s) -> 16B bf16 x-load (xbf) +
// 2x16B f32 out-store.
template<bool USE_XBF>
__global__ __launch_bounds__(256) void k_out(const float* __restrict__ x,
                                             const unsigned short* __restrict__ xbf,
                                             const unsigned short* __restrict__ att,
                                             const unsigned short* __restrict__ ytr,
                                             const float* __restrict__ scale,
                                             float* __restrict__ out){
  __shared__ float xt[4][16][36];  // per-wave 16x32 transpose buffer, stride 36
  int bid = blockIdx.x;            // 8n * 32ct * 8sb = 2048
  int sb = bid & 7;
  int ct = (bid >> 3) & 31;
  int n  = bid >> 8;
  int w  = threadIdx.x >> 6;
  int l  = threadIdx.x & 63, lo = l & 15, hi = l >> 4;
  int c0 = ct << 4;
  int s0 = (sb << 9) + (w << 7);   // 512 per block, 128 per wave
  float sc = scale[0];

  const unsigned short* ap = att + ((size_t)n * C_ + c0 + lo) * K_ + hi * 8;
  short8 a0 = *(const short8*)(ap);        // k = hi*8+j
  short8 a1 = *(const short8*)(ap + 32);   // k = 32 + hi*8+j

  const unsigned short* bp0 = ytr + ((size_t)n * HW_ + s0 + lo) * K_ + hi * 8;
  int row = l >> 2, c8 = (l & 3) << 3;     // epilogue: lane -> (row, 8 cols)
  size_t eoff = ((size_t)n * C_ + c0 + row) * HW_ + s0 + c8;
  const float*          xp = x   + eoff;
  const unsigned short* xq = xbf + eoff;
  float*                op = out + eoff;
  float (*T)[36] = xt[w];

#pragma unroll
  for (int p = 0; p < 4; ++p){
    const unsigned short* bp = bp0 + (size_t)(p * 32) * K_;
    short8 b0 = *(const short8*)(bp);
    short8 b1 = *(const short8*)(bp + 32);
    short8 b2 = *(const short8*)(bp + 16 * K_);
    short8 b3 = *(const short8*)(bp + 16 * K_ + 32);
    floatx4 acc0 = {0.f,0.f,0.f,0.f};
    floatx4 acc1 = {0.f,0.f,0.f,0.f};
    acc0 = __builtin_amdgcn_mfma_f32_16x16x32_bf16(a0, b0, acc0, 0, 0, 0);
    acc0 = __builtin_amdgcn_mfma_f32_16x16x32_bf16(a1, b1, acc0, 0, 0, 0);
    acc1 = __builtin_amdgcn_mfma_f32_16x16x32_bf16(a0, b2, acc1, 0, 0, 0);
    acc1 = __builtin_amdgcn_mfma_f32_16x16x32_bf16(a1, b3, acc1, 0, 0, 0);
    // acc layout: row = hi*4+r, col = lo (acc0: s+0..15, acc1: s+16..31)
#pragma unroll
    for (int r = 0; r < 4; ++r){
      T[hi * 4 + r][lo]      = acc0[r];
      T[hi * 4 + r][16 + lo] = acc1[r];
    }
    float4 v0 = *(const float4*)&T[row][c8];       // in-wave DS ordering
    float4 v1 = *(const float4*)&T[row][c8 + 4];
    float xf[8];
    if (USE_XBF){
      short8 xv = *(const short8*)(xq + p * 32);
#pragma unroll
      for (int j = 0; j < 8; ++j) xf[j] = bf2f((unsigned short)xv[j]);
    } else {
      float4 u0 = *(const float4*)(xp + p * 32);
      float4 u1 = *(const float4*)(xp + p * 32 + 4);
      xf[0]=u0.x; xf[1]=u0.y; xf[2]=u0.z; xf[3]=u0.w;
      xf[4]=u1.x; xf[5]=u1.y; xf[6]=u1.z; xf[7]=u1.w;
    }
    float4 o0, o1;
    o0.x = xf[0] + sc * v0.x; o0.y = xf[1] + sc * v0.y;
    o0.z = xf[2] + sc * v0.z; o0.w = xf[3] + sc * v0.w;
    o1.x = xf[4] + sc * v1.x; o1.y = xf[5] + sc * v1.y;
    o1.z = xf[6] + sc * v1.z; o1.w = xf[7] + sc * v1.w;
    *(float4*)(op + p * 32)     = o0;
    *(float4*)(op + p * 32 + 4) = o1;
  }
}

extern "C" void kernel_launch(void* const* d_in, const int* in_sizes, int n_in,
                              void* d_out, int out_size, void* d_ws, size_t ws_size,
                              hipStream_t stream){
  const float* x     = (const float*)d_in[0];
  const float* y     = (const float*)d_in[1];
  const float* scale = (const float*)d_in[2];
  float* out = (float*)d_out;

  // ws layout:
  //   partial : SPLITS * N*C*K f32  = 16 MiB      @ 0
  //   att     : N*C*K bf16          = 512 KiB     @ 16 MiB
  //   ybf     : N*K*HW bf16         = 4 MiB       @ 16.5 MiB
  //   ytr     : N*HW*K bf16         = 4 MiB       @ 20.5 MiB
  //   xbf     : N*C*HW bf16         = 32 MiB      @ 24.5 MiB (optional)
  char* ws = (char*)d_ws;
  float*          partial = (float*)(ws);
  unsigned short* att     = (unsigned short*)(ws + (16u<<20));
  unsigned short* ybf     = (unsigned short*)(ws + (16u<<20) + (512u<<10));
  unsigned short* ytr     = (unsigned short*)(ws + (16u<<20) + (512u<<10) + (4u<<20));
  unsigned short* xbf     = (unsigned short*)(ws + (24u<<20) + (512u<<10));
  bool use_xbf = ws_size >= ((56u<<20) + (512u<<10));

  k_prep   <<<N_ * (HW_/64),      256, 0, stream>>>(y, ybf, ytr);
  if (use_xbf){
    k_energy<true>  <<<N_ * 32 * 4, 256, 0, stream>>>(x, ybf, partial, xbf);
    k_softmax<<<(N_ * C_) / 4, 256, 0, stream>>>(partial, att);
    k_out<true>  <<<N_ * 32 * 8, 256, 0, stream>>>(x, xbf, att, ytr, scale, out);
  } else {
    k_energy<false> <<<N_ * 32 * 4, 256, 0, stream>>>(x, ybf, partial, xbf);
    k_softmax<<<(N_ * C_) / 4, 256, 0, stream>>>(partial, att);
    k_out<false> <<<N_ * 32 * 8, 256, 0, stream>>>(x, xbf, att, ytr, scale, out);
  }
}

// Round 5
// 62.655 us; speedup vs baseline: 1.1104x; 1.1104x over previous
//
#include <hip/hip_runtime.h>

// CCAMDec: out = x + scale * softmax(max_k(E)-E) @ y,  E = x·yᵀ over HW
// N=8, C=512, K=64, HW=4096. softmax(max-E) == softmax(-E) (shift invariance).
#define N_ 8
#define C_ 512
#define K_ 64
#define HW_ 4096
#define SPLITS 16
#define SRANGE (HW_ / SPLITS)   // 256

typedef __attribute__((ext_vector_type(8))) short short8;   // 8 bf16 (4 VGPRs) MFMA A/B frag
typedef __attribute__((ext_vector_type(4))) float floatx4;  // MFMA C/D frag

__device__ __forceinline__ float bf2f(unsigned short b){
  union { unsigned u; float f; } v; v.u = ((unsigned)b) << 16;
  return v.f;
}

// 8 f32 -> 8 bf16 via hardware v_cvt_pk_bf16_f32 (RNE, 1 instr / 2 elems)
__device__ __forceinline__ short8 cvt8(const float* __restrict__ p){
  float4 u = *(const float4*)p;
  float4 w = *(const float4*)(p + 4);
  union { unsigned u32[4]; short8 s; } r;
  asm("v_cvt_pk_bf16_f32 %0, %1, %2" : "=v"(r.u32[0]) : "v"(u.x), "v"(u.y));
  asm("v_cvt_pk_bf16_f32 %0, %1, %2" : "=v"(r.u32[1]) : "v"(u.z), "v"(u.w));
  asm("v_cvt_pk_bf16_f32 %0, %1, %2" : "=v"(r.u32[2]) : "v"(w.x), "v"(w.y));
  asm("v_cvt_pk_bf16_f32 %0, %1, %2" : "=v"(r.u32[3]) : "v"(w.z), "v"(w.w));
  return r.s;
}

// K0: y (f32, [n][k][s]) -> ybf (bf16 row-major [n][k][s]) and ytr (bf16 [n][s][k])
__global__ __launch_bounds__(256) void k_prep(const float* __restrict__ y,
                                              unsigned short* __restrict__ ybf,
                                              unsigned short* __restrict__ ytr){
  __shared__ unsigned short tile[64][72];
  int n  = blockIdx.x >> 6;                 // 64 s-tiles per batch
  int s0 = (blockIdx.x & 63) << 6;
  int tid = threadIdx.x;
  int k  = tid >> 2;
  int sc = (tid & 3) << 4;
  const float* yp = y + ((size_t)n * K_ + k) * HW_ + s0 + sc;
  union { unsigned short u16[16]; short8 s8[2]; uint4 q[2]; } u;
  u.s8[0] = cvt8(yp);
  u.s8[1] = cvt8(yp + 8);
  unsigned short* rp = ybf + ((size_t)n * K_ + k) * HW_ + s0 + sc;
  *(uint4*)rp       = u.q[0];
  *(uint4*)(rp + 8) = u.q[1];
#pragma unroll
  for (int j = 0; j < 16; ++j) tile[sc + j][k] = u.u16[j];
  __syncthreads();
  int s  = tid >> 2;
  int kc = (tid & 3) << 4;
  unsigned short* tp = ytr + ((size_t)n * HW_ + s0 + s) * K_ + kc;
  *(uint4*)tp       = *(const uint4*)&tile[s][kc];
  *(uint4*)(tp + 8) = *(const uint4*)&tile[s][kc + 8];
}

// K1: partial energies, LDS-staged GEMM. Block = (n, 64c-tile, 256s-range),
// 4 waves; 2 chunks of 128s. Staging: one global instr = one full row
// (512B f32 x / 256B ybf / 256B xbf store) -> fully lane-contiguous.
// LDS tiles [64 rows][128 elems] bf16, pitch 256B, XOR-swizzle ^((row&7)<<4)
// (guide §6 G4 verified geometry). Wave w computes c-rows w*16..w*16+15 x 64k.
template<bool WRITE_XBF>
__global__ __launch_bounds__(256) void k_energy(const float* __restrict__ x,
                                                const unsigned short* __restrict__ ybf,
                                                float* __restrict__ partial,
                                                unsigned short* __restrict__ xbf){
  __shared__ unsigned short As[64 * 128];   // 16 KB
  __shared__ unsigned short Bs[64 * 128];   // 16 KB
  int bid = blockIdx.x;            // 8n * 8ct * 16sp = 1024
  int sp = bid & 15;
  int ct = (bid >> 4) & 7;
  int n  = bid >> 7;
  int tid = threadIdx.x;
  int w = tid >> 6, l = tid & 63;
  int lo = l & 15, hi = l >> 4;
  int c0 = ct << 6;                // 64 c per block
  int sb = sp * SRANGE;            // 256 s per block
  int cw = w << 4;                 // wave's c-quadrant

  floatx4 acc0 = {0.f,0.f,0.f,0.f};
  floatx4 acc1 = acc0, acc2 = acc0, acc3 = acc0;

  int swz_st = (l * 4);            // staging: lane l writes dword l (pre-XOR)
  int swz_ld = (hi * 16) ^ ((lo & 7) << 4);

  for (int ch = 0; ch < 2; ++ch){
    int s0c = sb + ch * 128;
    // ---- stage: wave w owns rows w*16..w*16+15 of both A (c) and B (k) ----
#pragma unroll
    for (int i = 0; i < 16; ++i){
      int r = cw + i;              // r&7 == i&7
      int rx = (i & 7) << 4;
      const float* ga = x + ((size_t)n * C_ + c0 + r) * HW_ + s0c + l * 2;
      float2 v = *(const float2*)ga;
      unsigned d;
      asm("v_cvt_pk_bf16_f32 %0, %1, %2" : "=v"(d) : "v"(v.x), "v"(v.y));
      if (WRITE_XBF)
        *(unsigned*)(xbf + ((size_t)n * C_ + c0 + r) * HW_ + s0c + l * 2) = d;
      *(unsigned*)((char*)As + r * 256 + (swz_st ^ rx)) = d;
      unsigned db = *(const unsigned*)(ybf + ((size_t)n * K_ + r) * HW_ + s0c + l * 2);
      *(unsigned*)((char*)Bs + r * 256 + (swz_st ^ rx)) = db;
    }
    __syncthreads();
    // ---- compute: 4 ss-steps x 4 k-quadrants ----
#pragma unroll
    for (int ss = 0; ss < 4; ++ss){
      short8 a = *(const short8*)((const char*)As + (cw + lo) * 256 + ((ss * 64) ^ swz_ld ^ (ss * 64 & 0)) + ((ss * 64) & 0));
      // (ss*64 is 16B-chunk aligned and outside the XOR'd bits' overlap is fine:
      //  byte = row*256 + ((ss*64 + hi*16) ^ ((lo&7)<<4)) — XOR bits [6:4] vs ss bits [7:6]... compute directly:)
      a = *(const short8*)((const char*)As + (cw + lo) * 256 + (((ss * 64) + (hi * 16)) ^ ((lo & 7) << 4)));
      short8 b0 = *(const short8*)((const char*)Bs + ( 0 + lo) * 256 + (((ss * 64) + (hi * 16)) ^ ((lo & 7) << 4)));
      short8 b1 = *(const short8*)((const char*)Bs + (16 + lo) * 256 + (((ss * 64) + (hi * 16)) ^ ((lo & 7) << 4)));
      short8 b2 = *(const short8*)((const char*)Bs + (32 + lo) * 256 + (((ss * 64) + (hi * 16)) ^ ((lo & 7) << 4)));
      short8 b3 = *(const short8*)((const char*)Bs + (48 + lo) * 256 + (((ss * 64) + (hi * 16)) ^ ((lo & 7) << 4)));
      acc0 = __builtin_amdgcn_mfma_f32_16x16x32_bf16(a, b0, acc0, 0, 0, 0);
      acc1 = __builtin_amdgcn_mfma_f32_16x16x32_bf16(a, b1, acc1, 0, 0, 0);
      acc2 = __builtin_amdgcn_mfma_f32_16x16x32_bf16(a, b2, acc2, 0, 0, 0);
      acc3 = __builtin_amdgcn_mfma_f32_16x16x32_bf16(a, b3, acc3, 0, 0, 0);
    }
    __syncthreads();
  }

  // D layout: col = lo (k within quadrant), row = hi*4 + reg (c within 16)
  float* pp = partial + (((size_t)sp * N_ + n) * C_ + c0 + cw) * K_;
#pragma unroll
  for (int r = 0; r < 4; ++r){
    size_t coff = (size_t)(hi * 4 + r) * K_ + lo;
    pp[coff +  0] = acc0[r];
    pp[coff + 16] = acc1[r];
    pp[coff + 32] = acc2[r];
    pp[coff + 48] = acc3[r];
  }
}

// K2: reduce splits + softmax(-E) over k (wave-wide, K=64=wavefront), att -> bf16
__global__ __launch_bounds__(256) void k_softmax(const float* __restrict__ partial,
                                                 unsigned short* __restrict__ att){
  int wid = blockIdx.x * 4 + (threadIdx.x >> 6);  // (n,c) row id, 0..4095
  int l = threadIdx.x & 63;
  size_t base = (size_t)wid * K_ + l;
  float e = 0.f;
#pragma unroll
  for (int sp = 0; sp < SPLITS; ++sp) e += partial[(size_t)sp * (N_*C_*K_) + base];
  // softmax(-e): stabilize with min(e)
  float m = e;
#pragma unroll
  for (int off = 32; off > 0; off >>= 1) m = fminf(m, __shfl_xor(m, off));
  float p = __expf(m - e);
  float sum = p;
#pragma unroll
  for (int off = 32; off > 0; off >>= 1) sum += __shfl_xor(sum, off);
  union { unsigned u; float f; } v; v.f = p / sum;
  unsigned r = v.u + 0x7FFFu + ((v.u >> 16) & 1u);
  att[base] = (unsigned short)(r >> 16);
}

// K3: out = x + scale * att @ y.  4 waves/block; block tile 16c x 512s
// (128s per wave). Epilogue: per 32-s double-subtile, transpose acc through
// LDS so each lane owns (1 row, 8 consecutive s) -> 16B bf16 x-load (xbf) +
// 2x16B f32 out-store.
template<bool USE_XBF>
__global__ __launch_bounds__(256) void k_out(const float* __restrict__ x,
                                             const unsigned short* __restrict__ xbf,
                                             const unsigned short* __restrict__ att,
                                             const unsigned short* __restrict__ ytr,
                                             const float* __restrict__ scale,
                                             float* __restrict__ out){
  __shared__ float xt[4][16][36];  // per-wave 16x32 transpose buffer, stride 36
  int bid = blockIdx.x;            // 8n * 32ct * 8sb = 2048
  int sb = bid & 7;
  int ct = (bid >> 3) & 31;
  int n  = bid >> 8;
  int w  = threadIdx.x >> 6;
  int l  = threadIdx.x & 63, lo = l & 15, hi = l >> 4;
  int c0 = ct << 4;
  int s0 = (sb << 9) + (w << 7);   // 512 per block, 128 per wave
  float sc = scale[0];

  const unsigned short* ap = att + ((size_t)n * C_ + c0 + lo) * K_ + hi * 8;
  short8 a0 = *(const short8*)(ap);        // k = hi*8+j
  short8 a1 = *(const short8*)(ap + 32);   // k = 32 + hi*8+j

  const unsigned short* bp0 = ytr + ((size_t)n * HW_ + s0 + lo) * K_ + hi * 8;
  int row = l >> 2, c8 = (l & 3) << 3;     // epilogue: lane -> (row, 8 cols)
  size_t eoff = ((size_t)n * C_ + c0 + row) * HW_ + s0 + c8;
  const float*          xp = x   + eoff;
  const unsigned short* xq = xbf + eoff;
  float*                op = out + eoff;
  float (*T)[36] = xt[w];

#pragma unroll
  for (int p = 0; p < 4; ++p){
    const unsigned short* bp = bp0 + (size_t)(p * 32) * K_;
    short8 b0 = *(const short8*)(bp);
    short8 b1 = *(const short8*)(bp + 32);
    short8 b2 = *(const short8*)(bp + 16 * K_);
    short8 b3 = *(const short8*)(bp + 16 * K_ + 32);
    floatx4 acc0 = {0.f,0.f,0.f,0.f};
    floatx4 acc1 = {0.f,0.f,0.f,0.f};
    acc0 = __builtin_amdgcn_mfma_f32_16x16x32_bf16(a0, b0, acc0, 0, 0, 0);
    acc0 = __builtin_amdgcn_mfma_f32_16x16x32_bf16(a1, b1, acc0, 0, 0, 0);
    acc1 = __builtin_amdgcn_mfma_f32_16x16x32_bf16(a0, b2, acc1, 0, 0, 0);
    acc1 = __builtin_amdgcn_mfma_f32_16x16x32_bf16(a1, b3, acc1, 0, 0, 0);
    // acc layout: row = hi*4+r, col = lo (acc0: s+0..15, acc1: s+16..31)
#pragma unroll
    for (int r = 0; r < 4; ++r){
      T[hi * 4 + r][lo]      = acc0[r];
      T[hi * 4 + r][16 + lo] = acc1[r];
    }
    float4 v0 = *(const float4*)&T[row][c8];       // in-wave DS ordering
    float4 v1 = *(const float4*)&T[row][c8 + 4];
    float xf[8];
    if (USE_XBF){
      short8 xv = *(const short8*)(xq + p * 32);
#pragma unroll
      for (int j = 0; j < 8; ++j) xf[j] = bf2f((unsigned short)xv[j]);
    } else {
      float4 u0 = *(const float4*)(xp + p * 32);
      float4 u1 = *(const float4*)(xp + p * 32 + 4);
      xf[0]=u0.x; xf[1]=u0.y; xf[2]=u0.z; xf[3]=u0.w;
      xf[4]=u1.x; xf[5]=u1.y; xf[6]=u1.z; xf[7]=u1.w;
    }
    float4 o0, o1;
    o0.x = xf[0] + sc * v0.x; o0.y = xf[1] + sc * v0.y;
    o0.z = xf[2] + sc * v0.z; o0.w = xf[3] + sc * v0.w;
    o1.x = xf[4] + sc * v1.x; o1.y = xf[5] + sc * v1.y;
    o1.z = xf[6] + sc * v1.z; o1.w = xf[7] + sc * v1.w;
    *(float4*)(op + p * 32)     = o0;
    *(float4*)(op + p * 32 + 4) = o1;
  }
}

extern "C" void kernel_launch(void* const* d_in, const int* in_sizes, int n_in,
                              void* d_out, int out_size, void* d_ws, size_t ws_size,
                              hipStream_t stream){
  const float* x     = (const float*)d_in[0];
  const float* y     = (const float*)d_in[1];
  const float* scale = (const float*)d_in[2];
  float* out = (float*)d_out;

  // ws layout:
  //   partial : SPLITS * N*C*K f32  = 16 MiB      @ 0
  //   att     : N*C*K bf16          = 512 KiB     @ 16 MiB
  //   ybf     : N*K*HW bf16         = 4 MiB       @ 16.5 MiB
  //   ytr     : N*HW*K bf16         = 4 MiB       @ 20.5 MiB
  //   xbf     : N*C*HW bf16         = 32 MiB      @ 24.5 MiB (optional)
  char* ws = (char*)d_ws;
  float*          partial = (float*)(ws);
  unsigned short* att     = (unsigned short*)(ws + (16u<<20));
  unsigned short* ybf     = (unsigned short*)(ws + (16u<<20) + (512u<<10));
  unsigned short* ytr     = (unsigned short*)(ws + (16u<<20) + (512u<<10) + (4u<<20));
  unsigned short* xbf     = (unsigned short*)(ws + (24u<<20) + (512u<<10));
  bool use_xbf = ws_size >= ((56u<<20) + (512u<<10));

  k_prep   <<<N_ * (HW_/64),      256, 0, stream>>>(y, ybf, ytr);
  if (use_xbf){
    k_energy<true>  <<<N_ * 8 * 16, 256, 0, stream>>>(x, ybf, partial, xbf);
    k_softmax<<<(N_ * C_) / 4, 256, 0, stream>>>(partial, att);
    k_out<true>  <<<N_ * 32 * 8, 256, 0, stream>>>(x, xbf, att, ytr, scale, out);
  } else {
    k_energy<false> <<<N_ * 8 * 16, 256, 0, stream>>>(x, ybf, partial, xbf);
    k_softmax<<<(N_ * C_) / 4, 256, 0, stream>>>(partial, att);
    k_out<false> <<<N_ * 32 * 8, 256, 0, stream>>>(x, xbf, att, ytr, scale, out);
  }
}